// Round 29
// baseline (266.611 us; speedup 1.0000x reference)
//
#include <hip/hip_runtime.h>
#include <math.h>

#define FIN 512
#define FH 128
#define FOUT 40
#define FP 64     // padded H2 width
#define NB 512    // partition buckets
#define PSLOTS 14 // LDS slots per bucket (512*14*4 + 512*4 = 30.7KB <= 32KB)
#define CAPG 4096 // gbuf capacity per bucket (mean ~3125)
#define PBLK 512  // partition blocks

typedef unsigned char u8;
typedef __attribute__((ext_vector_type(8))) short bf16x8;
typedef __attribute__((ext_vector_type(4))) float f32x4;
typedef __attribute__((ext_vector_type(2))) float f32x2;

__device__ inline ushort f2bf(float f){
  union { float f; uint32_t u; } v; v.f = f;
  uint32_t u = v.u;
  uint32_t r = (u + 0x7FFF + ((u >> 16) & 1)) >> 16;
  return (ushort)r;
}
__device__ inline uint32_t cvtpk(float a, float b){
  uint32_t r;
  asm("v_cvt_pk_bf16_f32 %0, %1, %2" : "=v"(r) : "v"(a), "v"(b));
  return r;
}
__device__ inline f32x2 pkadd(f32x2 a, f32x2 b){
  f32x2 r;
  asm("v_pk_add_f32 %0, %1, %2" : "=v"(r) : "v"(a), "v"(b));
  return r;
}
__device__ inline f32x2 pkfma(f32x2 a, f32x2 b, f32x2 c){
  f32x2 r;
  asm("v_pk_fma_f32 %0, %1, %2, %3" : "=v"(r) : "v"(a), "v"(b), "v"(c));
  return r;
}
__device__ inline f32x2 f8lo(uint32_t v){ return __builtin_amdgcn_cvt_pk_f32_fp8(v, false); }
__device__ inline f32x2 f8hi(uint32_t v){ return __builtin_amdgcn_cvt_pk_f32_fp8(v, true); }
__device__ inline u8 f2f8(float v){
  return (u8)(__builtin_amdgcn_cvt_pk_fp8_f32(v, v, 0, false) & 0xFF);
}

// ---------------- k_prep: weight conversion (standalone) ----------------
__global__ __launch_bounds__(256) void k_prep(const float* __restrict__ W1,
                                              const float* __restrict__ W2,
                                              ushort* __restrict__ W1t, ushort* __restrict__ W2t){
  int i = blockIdx.x*256 + threadIdx.x;
  if(i < FIN*FH){
    int k = i / FH, c = i % FH;
    W1t[(size_t)c*FIN + k] = f2bf(W1[i]);
  }
  if(i < 48*FH){
    int c = i / FH, k = i % FH;
    W2t[i] = (c < FOUT) ? f2bf(W2[(size_t)k*FOUT + c]) : (ushort)0;
  }
}

// ---------------- FUSED: gemm1 (unscaled XW->fp8) || k_part, BOTH within 32KB LDS --------
// Odd blocks: edge partition (PSLOTS=14 buffers, 30.7KB). Even blocks: gemm1 (32KB staging).
// Whole kernel LDS = 32KB -> 4 blocks/CU co-residency for real overlap.
__global__ __launch_bounds__(512, 2) void k_gemm1_part(const float* __restrict__ X,
                                                       const ushort* __restrict__ W1t,
                                                       u8* __restrict__ XWs, int n, int G,
                                                       const int* __restrict__ src,
                                                       const int* __restrict__ dst, int e,
                                                       int* __restrict__ gcur,
                                                       uint32_t* __restrict__ gbuf, int npb){
  __shared__ char smem[32768];
  int b = blockIdx.x;
  int t = threadIdx.x;

  if(b & 1){
    // ---- partition (LDS bucket buffers, PSLOTS=14) ----
    int pidx = b >> 1;
    if(pidx >= PBLK) return;
    uint32_t* pbuf = (uint32_t*)smem;                // NB*PSLOTS = 28672 B
    int* lcnt = (int*)(smem + NB*PSLOTS*4);          // 2048 B
    if(t < NB) lcnt[t] = 0;
    __syncthreads();
    int chunk = (e + PBLK - 1) / PBLK;
    int base = pidx * chunk;
    int endE = base + chunk; if(endE > e) endE = e;
    if(base >= e) return;
    int rounds = (endE - base + 511) / 512;
    for(int rr=0; rr<rounds; ++rr){
      int i = base + rr*512 + t;
      if(i < endE){
        int s = src[i];
        int d = dst[i];
        int bk = d / npb;
        uint32_t pk_ = ((uint32_t)s << 8) | (uint32_t)(d - bk*npb);
        int slot = atomicAdd(&lcnt[bk], 1);
        if(slot < PSLOTS){
          pbuf[bk*PSLOTS + slot] = pk_;
        } else {
          int g = atomicAdd(&gcur[bk], 1);
          gbuf[(size_t)bk*CAPG + g] = pk_;
        }
      }
      __syncthreads();
      bool last = (rr == rounds-1);
      if(t < NB){
        int c = lcnt[t];
        int k = c < PSLOTS ? c : PSLOTS;
        if(k > 0 && (k >= 8 || last)){
          int g = atomicAdd(&gcur[t], k);
          uint32_t* dstp = &gbuf[(size_t)t*CAPG + g];
          const uint32_t* srcp = &pbuf[t*PSLOTS];
          for(int q=0; q<k; q++) dstp[q] = srcp[q];
          lcnt[t] = 0;
        }
      }
      __syncthreads();
    }
    return;
  }

  // ---- gemm1 (r27 body; stores UNSCALED fp8) ----
  int gi = b >> 1;
  if(gi >= G) return;
  int lane = t & 63;
  int wid = t >> 6;
  int l15 = lane & 15;
  int lk8 = (lane >> 4) * 8;
  int rowbase = gi * 256 + wid * 32;

  int r0 = rowbase + l15;      if (r0 >= n) r0 = n-1;
  int r1 = rowbase + 16 + l15; if (r1 >= n) r1 = n-1;
  const float* a0p = X + (size_t)r0*FIN;
  const float* a1p = X + (size_t)r1*FIN;

  f32x4 acc[2][8];
  #pragma unroll
  for(int i=0;i<2;i++)
    #pragma unroll
    for(int j=0;j<8;j++) acc[i][j] = (f32x4){0.f,0.f,0.f,0.f};

  char* WsB = smem;

  for(int ph=0; ph<4; ph++){
    if(ph) __syncthreads();
    #pragma unroll
    for(int it=0; it<4; it++){
      int c = it*512 + t;
      int col = c >> 4, kslot = c & 15;
      uint4 v = *(const uint4*)(W1t + (size_t)col*FIN + ph*128 + kslot*8);
      int dstb = col*256 + ((kslot*16) ^ ((col & 7) << 4));
      *(uint4*)(WsB + dstb) = v;
    }
    __syncthreads();

    for(int kc=0; kc<4; kc++){
      int kl = kc*32 + lk8;
      int kg = ph*128 + kl;
      float4 a0a = *(const float4*)(a0p + kg);
      float4 a0b = *(const float4*)(a0p + kg + 4);
      float4 a1a = *(const float4*)(a1p + kg);
      float4 a1b = *(const float4*)(a1p + kg + 4);
      uint4 fa0u, fa1u;
      fa0u.x = cvtpk(a0a.x, a0a.y); fa0u.y = cvtpk(a0a.z, a0a.w);
      fa0u.z = cvtpk(a0b.x, a0b.y); fa0u.w = cvtpk(a0b.z, a0b.w);
      fa1u.x = cvtpk(a1a.x, a1a.y); fa1u.y = cvtpk(a1a.z, a1a.w);
      fa1u.z = cvtpk(a1b.x, a1b.y); fa1u.w = cvtpk(a1b.z, a1b.w);
      bf16x8 fa0 = *(bf16x8*)&fa0u;
      bf16x8 fa1 = *(bf16x8*)&fa1u;

      #pragma unroll
      for(int fj=0; fj<8; fj++){
        int col = fj*16 + l15;
        int srcb = col*256 + ((kl*2) ^ ((col & 7) << 4));
        bf16x8 fb = *(const bf16x8*)(WsB + srcb);
        acc[0][fj] = __builtin_amdgcn_mfma_f32_16x16x32_bf16(fa0, fb, acc[0][fj], 0, 0, 0);
        acc[1][fj] = __builtin_amdgcn_mfma_f32_16x16x32_bf16(fa1, fb, acc[1][fj], 0, 0, 0);
      }
    }
  }

  int rbase = (lane >> 4) * 4;
  #pragma unroll
  for(int fi=0; fi<2; fi++){
    #pragma unroll
    for(int r=0; r<4; r++){
      int row = rowbase + fi*16 + rbase + r;
      if(row < n){
        #pragma unroll
        for(int fj=0; fj<8; fj++){
          XWs[(size_t)row*FH + fj*16 + l15] = f2f8(acc[fi][fj][r]);
        }
      }
    }
  }
}

// ---------------- k_scan_g: exclusive scan of gcur -> bucket CSR start offsets ----------
__global__ __launch_bounds__(512) void k_scan_g(const int* __restrict__ gcur,
                                                int* __restrict__ bstart){
  __shared__ int sh[512];
  int t = threadIdx.x;
  sh[t] = gcur[t];
  __syncthreads();
  for(int off=1; off<512; off<<=1){
    int x = (t>=off)? sh[t-off]:0; __syncthreads();
    sh[t]+=x; __syncthreads();
  }
  bstart[t] = (t>0)? sh[t-1] : 0;
}

// ---------------- k_histfill: per-bucket hist + local scan + rp/dinv + CSR scatter -------
__global__ __launch_bounds__(256) void k_histfill(const uint32_t* __restrict__ gbuf,
                                                  const int* __restrict__ gcur,
                                                  const int* __restrict__ bstart,
                                                  int* __restrict__ rp, float* __restrict__ dinv,
                                                  int* __restrict__ srcs, int n, int npb){
  __shared__ int hist[256];
  __shared__ int sh[256];
  __shared__ int lcur[256];
  int b = blockIdx.x, t = threadIdx.x;
  int base = b * npb;
  if(base >= n) return;
  int nn = n - base; if(nn > npb) nn = npb;
  hist[t] = 0;
  __syncthreads();
  int m = gcur[b];
  const uint32_t* bp = gbuf + (size_t)b*CAPG;
  for(int i=t; i<m; i+=256) atomicAdd(&hist[bp[i] & 255u], 1);
  __syncthreads();
  int v = hist[t];
  sh[t] = v;
  __syncthreads();
  for(int off=1; off<256; off<<=1){
    int x = (t>=off)? sh[t-off]:0; __syncthreads();
    sh[t]+=x; __syncthreads();
  }
  int bs = bstart[b];
  if(t < nn){
    rp[base+t+1] = bs + sh[t];
    dinv[base+t] = rsqrtf((float)(v+1));
    lcur[t] = bs + sh[t] - v;
  }
  if(b==0 && t==0) rp[0] = 0;
  __syncthreads();
  for(int i=t; i<m; i+=256){
    uint32_t w = bp[i];
    int ld = (int)(w & 255u);
    int p = atomicAdd(&lcur[ld], 1);
    srcs[p] = (int)(w >> 8);
  }
}

// ---------------- agg1: H1b = relu(dd*(sum_s XW[s]*dinv[s] + XW[d]*dd) + b1) -------------
__global__ __launch_bounds__(256) void k_agg1(const u8* __restrict__ XWs, const int* __restrict__ rp,
                                              const int* __restrict__ srcs, const float* __restrict__ dinv,
                                              const float* __restrict__ b1, ushort* __restrict__ H1b, int n){
  int d = blockIdx.x*4 + (threadIdx.x >> 6);
  if(d >= n) return;
  int lane = threadIdx.x & 63;
  int g = lane >> 3, li = lane & 7;
  f32x2 acc[8];
  #pragma unroll
  for(int k=0;k<8;k++) acc[k] = (f32x2){0.f,0.f};
  int beg = rp[d];
  int end = rp[d+1];
  int j = beg + g;
  bool h0 = j < end, h1 = j + 8 < end;
  int s0 = 0, s1 = 0;
  float ds0 = 0.f, ds1 = 0.f;
  if(h0){ s0 = srcs[j];   ds0 = dinv[s0]; }
  if(h1){ s1 = srcs[j+8]; ds1 = dinv[s1]; }
  while(h1){
    int nj = j + 16;
    bool nh0 = nj < end, nh1 = nj + 8 < end;
    int ns0 = 0, ns1 = 0;
    float nds0 = 0.f, nds1 = 0.f;
    if(nh0){ ns0 = srcs[nj];   nds0 = dinv[ns0]; }
    if(nh1){ ns1 = srcs[nj+8]; nds1 = dinv[ns1]; }
    uint4 a0 = *(const uint4*)(XWs + (size_t)s0*FH + li*16);
    uint4 c0 = *(const uint4*)(XWs + (size_t)s1*FH + li*16);
    f32x2 d0v = {ds0, ds0};
    f32x2 d1v = {ds1, ds1};
    acc[0] = pkfma(f8lo(a0.x), d0v, acc[0]); acc[0] = pkfma(f8lo(c0.x), d1v, acc[0]);
    acc[1] = pkfma(f8hi(a0.x), d0v, acc[1]); acc[1] = pkfma(f8hi(c0.x), d1v, acc[1]);
    acc[2] = pkfma(f8lo(a0.y), d0v, acc[2]); acc[2] = pkfma(f8lo(c0.y), d1v, acc[2]);
    acc[3] = pkfma(f8hi(a0.y), d0v, acc[3]); acc[3] = pkfma(f8hi(c0.y), d1v, acc[3]);
    acc[4] = pkfma(f8lo(a0.z), d0v, acc[4]); acc[4] = pkfma(f8lo(c0.z), d1v, acc[4]);
    acc[5] = pkfma(f8hi(a0.z), d0v, acc[5]); acc[5] = pkfma(f8hi(c0.z), d1v, acc[5]);
    acc[6] = pkfma(f8lo(a0.w), d0v, acc[6]); acc[6] = pkfma(f8lo(c0.w), d1v, acc[6]);
    acc[7] = pkfma(f8hi(a0.w), d0v, acc[7]); acc[7] = pkfma(f8hi(c0.w), d1v, acc[7]);
    j = nj; s0 = ns0; s1 = ns1; ds0 = nds0; ds1 = nds1; h0 = nh0; h1 = nh1;
  }
  if(h0){
    uint4 a0 = *(const uint4*)(XWs + (size_t)s0*FH + li*16);
    f32x2 d0v = {ds0, ds0};
    acc[0] = pkfma(f8lo(a0.x), d0v, acc[0]);
    acc[1] = pkfma(f8hi(a0.x), d0v, acc[1]);
    acc[2] = pkfma(f8lo(a0.y), d0v, acc[2]);
    acc[3] = pkfma(f8hi(a0.y), d0v, acc[3]);
    acc[4] = pkfma(f8lo(a0.z), d0v, acc[4]);
    acc[5] = pkfma(f8hi(a0.z), d0v, acc[5]);
    acc[6] = pkfma(f8lo(a0.w), d0v, acc[6]);
    acc[7] = pkfma(f8hi(a0.w), d0v, acc[7]);
  }
  #pragma unroll
  for(int k=0;k<8;k++){
    #pragma unroll
    for(int c=0;c<2;c++){
      acc[k][c] += __shfl_xor(acc[k][c], 8);
      acc[k][c] += __shfl_xor(acc[k][c], 16);
      acc[k][c] += __shfl_xor(acc[k][c], 32);
    }
  }
  if(g == 0){
    uint4 sv4 = *(const uint4*)(XWs + (size_t)d*FH + li*16);
    f32x2 slf[8];
    slf[0]=f8lo(sv4.x); slf[1]=f8hi(sv4.x); slf[2]=f8lo(sv4.y); slf[3]=f8hi(sv4.y);
    slf[4]=f8lo(sv4.z); slf[5]=f8hi(sv4.z); slf[6]=f8lo(sv4.w); slf[7]=f8hi(sv4.w);
    float dd = dinv[d];
    uint32_t w[8];
    #pragma unroll
    for(int k=0;k<8;k++){
      float b0 = b1[li*16 + k*2];
      float b1v = b1[li*16 + k*2 + 1];
      float o0 = fmaxf((acc[k][0] + slf[k][0]*dd)*dd + b0, 0.f);
      float o1 = fmaxf((acc[k][1] + slf[k][1]*dd)*dd + b1v, 0.f);
      w[k] = cvtpk(o0, o1);
    }
    uint4 w0 = {w[0],w[1],w[2],w[3]};
    uint4 w1 = {w[4],w[5],w[6],w[7]};
    uint4* wp = (uint4*)(H1b + (size_t)d*FH + li*16);
    wp[0] = w0;
    wp[1] = w1;
  }
}

// ---------------- GEMM2 via MFMA: H2s[n,64] fp8 = (H1b @ W2) * dinv[row] ----------------
__global__ __launch_bounds__(256) void k_gemm2_mfma(const ushort* __restrict__ H1b,
                                                    const ushort* __restrict__ W2t,
                                                    const float* __restrict__ dinv,
                                                    u8* __restrict__ H2s, int n){
  int t = threadIdx.x;
  int lane = t & 63;
  int wid = t >> 6;
  int l15 = lane & 15;
  int lk8 = (lane >> 4) * 8;
  int rowbase = blockIdx.x * 128 + wid * 32;

  int r0 = rowbase + l15;      if (r0 >= n) r0 = n-1;
  int r1 = rowbase + 16 + l15; if (r1 >= n) r1 = n-1;
  const ushort* a0p = H1b + (size_t)r0*FH + lk8;
  const ushort* a1p = H1b + (size_t)r1*FH + lk8;

  f32x4 acc[2][3];
  #pragma unroll
  for(int i=0;i<2;i++)
    #pragma unroll
    for(int j=0;j<3;j++) acc[i][j] = (f32x4){0.f,0.f,0.f,0.f};

  #pragma unroll
  for(int kc=0; kc<4; kc++){
    int k0 = kc*32;
    bf16x8 fa0 = *(const bf16x8*)(a0p + k0);
    bf16x8 fa1 = *(const bf16x8*)(a1p + k0);
    #pragma unroll
    for(int fj=0; fj<3; fj++){
      bf16x8 fb = *(const bf16x8*)(W2t + (size_t)(fj*16 + l15)*FH + k0 + lk8);
      acc[0][fj] = __builtin_amdgcn_mfma_f32_16x16x32_bf16(fa0, fb, acc[0][fj], 0, 0, 0);
      acc[1][fj] = __builtin_amdgcn_mfma_f32_16x16x32_bf16(fa1, fb, acc[1][fj], 0, 0, 0);
    }
  }

  int rbase = (lane >> 4) * 4;
  #pragma unroll
  for(int fi=0; fi<2; fi++){
    #pragma unroll
    for(int r=0; r<4; r++){
      int row = rowbase + fi*16 + rbase + r;
      if(row < n){
        float dd = dinv[row];
        #pragma unroll
        for(int fj=0; fj<3; fj++){
          int col = fj*16 + l15;
          H2s[(size_t)row*FP + col] = (col < FOUT) ? f2f8(acc[fi][fj][r] * dd) : (u8)0;
        }
        H2s[(size_t)row*FP + 48 + l15] = (u8)0;
      }
    }
  }
}

// ---------------- agg2 + bias + log_softmax, fp8 gather (H2s prescaled) ----------------
__global__ __launch_bounds__(256) void k_agg2_sm(const u8* __restrict__ H2s, const int* __restrict__ rp,
                                                 const int* __restrict__ srcs, const float* __restrict__ dinv,
                                                 const float* __restrict__ b2, float* __restrict__ out, int n){
  int d = blockIdx.x*4 + (threadIdx.x >> 6);
  if(d >= n) return;
  int lane = threadIdx.x & 63;
  int g = lane >> 3, li = lane & 7;
  f32x2 acc[4];
  #pragma unroll
  for(int k=0;k<4;k++) acc[k] = (f32x2){0.f,0.f};
  int beg = rp[d];
  int end = rp[d+1];
  int j = beg + g;
  bool h0 = j < end, h1 = j + 8 < end;
  int s0 = 0, s1 = 0;
  if(h0) s0 = srcs[j];
  if(h1) s1 = srcs[j+8];
  while(h1){
    int nj = j + 16;
    bool nh0 = nj < end, nh1 = nj + 8 < end;
    int ns0 = 0, ns1 = 0;
    if(nh0) ns0 = srcs[nj];
    if(nh1) ns1 = srcs[nj+8];
    uint2 v = *(const uint2*)(H2s + (size_t)s0*FP + li*8);
    uint2 u = *(const uint2*)(H2s + (size_t)s1*FP + li*8);
    acc[0] = pkadd(acc[0], pkadd(f8lo(v.x), f8lo(u.x)));
    acc[1] = pkadd(acc[1], pkadd(f8hi(v.x), f8hi(u.x)));
    acc[2] = pkadd(acc[2], pkadd(f8lo(v.y), f8lo(u.y)));
    acc[3] = pkadd(acc[3], pkadd(f8hi(v.y), f8hi(u.y)));
    j = nj; s0 = ns0; s1 = ns1; h0 = nh0; h1 = nh1;
  }
  if(h0){
    uint2 v = *(const uint2*)(H2s + (size_t)s0*FP + li*8);
    acc[0] = pkadd(acc[0], f8lo(v.x));
    acc[1] = pkadd(acc[1], f8hi(v.x));
    acc[2] = pkadd(acc[2], f8lo(v.y));
    acc[3] = pkadd(acc[3], f8hi(v.y));
  }
  #pragma unroll
  for(int k=0;k<4;k++){
    #pragma unroll
    for(int c=0;c<2;c++){
      acc[k][c] += __shfl_xor(acc[k][c], 8);
      acc[k][c] += __shfl_xor(acc[k][c], 16);
      acc[k][c] += __shfl_xor(acc[k][c], 32);
    }
  }
  uint2 sv = *(const uint2*)(H2s + (size_t)d*FP + li*8);
  f32x2 s2[4] = { f8lo(sv.x), f8hi(sv.x), f8lo(sv.y), f8hi(sv.y) };
  float dd = dinv[d];
  float val[8];
  #pragma unroll
  for(int k=0;k<4;k++){
    #pragma unroll
    for(int c=0;c<2;c++){
      int col = li*8 + k*2 + c;
      float bv = (col < FOUT) ? b2[col] : 0.f;
      val[k*2+c] = (col < FOUT) ? ((acc[k][c]+s2[k][c])*dd + bv) : -3.402823466e38f;
    }
  }
  float m = val[0];
  #pragma unroll
  for(int k=1;k<8;k++) m = fmaxf(m, val[k]);
  #pragma unroll
  for(int off=1; off<8; off<<=1) m = fmaxf(m, __shfl_xor(m, off));
  float ssum = 0.f;
  #pragma unroll
  for(int k=0;k<8;k++){
    int col = li*8 + k;
    ssum += (col < FOUT) ? expf(val[k] - m) : 0.f;
  }
  #pragma unroll
  for(int off=1; off<8; off<<=1) ssum += __shfl_xor(ssum, off);
  float lse = m + logf(ssum);
  if(g == 0 && li < 5){
    float4 o0 = {val[0]-lse, val[1]-lse, val[2]-lse, val[3]-lse};
    float4 o1 = {val[4]-lse, val[5]-lse, val[6]-lse, val[7]-lse};
    float* op = out + (size_t)d*FOUT + li*8;
    *(float4*)op = o0;
    *(float4*)(op+4) = o1;
  }
}

// ---------------- launch ----------------

extern "C" void kernel_launch(void* const* d_in, const int* in_sizes, int n_in,
                              void* d_out, int out_size, void* d_ws, size_t ws_size,
                              hipStream_t stream){
  const float* X  = (const float*)d_in[0];
  const int*   ei = (const int*)d_in[1];
  const float* W1 = (const float*)d_in[2];
  const float* b1 = (const float*)d_in[3];
  const float* W2 = (const float*)d_in[4];
  const float* b2 = (const float*)d_in[5];
  float* out = (float*)d_out;

  int n = in_sizes[0] / FIN;      // 100000
  int e = in_sizes[1] / 2;        // 1600000
  const int* src = ei;
  const int* dst = ei + e;

  int npb = (n + NB - 1) / NB;    // 196

  // workspace layout
  u8* XWs     = (u8*)d_ws;                           // n*128 fp8 (UNSCALED XW)
  ushort* H1b = (ushort*)(XWs + (size_t)n*FH);       // n*128 bf16 (gbuf overlay pre-agg1)
  u8* H2s     = (u8*)(H1b + (size_t)n*FH);           // n*64 fp8 (dinv-scaled, padded)
  ushort* W1t = (ushort*)(H2s + (size_t)n*FP);       // 128*512 bf16
  ushort* W2t = W1t + (size_t)FH*FIN;                // 48*128 bf16
  float* dinv = (float*)(W2t + 48*FH);               // n
  int* gcur   = (int*)(dinv + n);                    // NB
  int* bstart = gcur + NB;                           // NB
  int* rp     = bstart + NB;                         // n+1
  int* srcs   = rp + (n+1) + 3;                      // e
  uint32_t* gbuf = (uint32_t*)H1b;                   // NB*CAPG*4B = 8.4MB

  int G = (n + 255) / 256;                   // gemm1 blocks (256 rows each)
  int T = 2 * ((G > PBLK) ? G : PBLK);       // fused grid: even=gemm1, odd=part

  hipMemsetAsync(gcur, 0, (size_t)NB*sizeof(int), stream);
  hipLaunchKernelGGL(k_prep, dim3((FIN*FH+255)/256), dim3(256), 0, stream, W1, W2, W1t, W2t);
  hipLaunchKernelGGL(k_gemm1_part, dim3(T), dim3(512), 0, stream,
                     X, W1t, XWs, n, G, src, dst, e, gcur, gbuf, npb);
  hipLaunchKernelGGL(k_scan_g, dim3(1), dim3(512), 0, stream, gcur, bstart);
  hipLaunchKernelGGL(k_histfill, dim3(NB), dim3(256), 0, stream,
                     gbuf, gcur, bstart, rp, dinv, srcs, n, npb);

  hipLaunchKernelGGL(k_agg1, dim3((n+3)/4), dim3(256), 0, stream, XWs, rp, srcs, dinv, b1, H1b, n);
  hipLaunchKernelGGL(k_gemm2_mfma, dim3((n+127)/128), dim3(256), 0, stream, H1b, W2t, dinv, H2s, n);
  hipLaunchKernelGGL(k_agg2_sm, dim3((n+3)/4), dim3(256), 0, stream, H2s, rp, srcs, dinv, b2, out, n);
}

// Round 30
// 239.079 us; speedup vs baseline: 1.1152x; 1.1152x over previous
//
#include <hip/hip_runtime.h>
#include <math.h>

#define FIN 512
#define FH 128
#define FOUT 40
#define FP 64     // padded H2 width
#define NB 512    // partition buckets
#define PSLOTS 30 // LDS slots per bucket (512*30*4 + 512*4 = 63.5KB)
#define CAPG 4096 // gbuf capacity per bucket (mean ~3125, +6sigma < 3500)
#define PBLK 512  // partition blocks

typedef unsigned char u8;
typedef __attribute__((ext_vector_type(8))) short bf16x8;
typedef __attribute__((ext_vector_type(4))) float f32x4;
typedef __attribute__((ext_vector_type(2))) float f32x2;

__device__ inline ushort f2bf(float f){
  union { float f; uint32_t u; } v; v.f = f;
  uint32_t u = v.u;
  uint32_t r = (u + 0x7FFF + ((u >> 16) & 1)) >> 16;
  return (ushort)r;
}
__device__ inline uint32_t cvtpk(float a, float b){
  uint32_t r;
  asm("v_cvt_pk_bf16_f32 %0, %1, %2" : "=v"(r) : "v"(a), "v"(b));
  return r;
}
__device__ inline f32x2 pkadd(f32x2 a, f32x2 b){
  f32x2 r;
  asm("v_pk_add_f32 %0, %1, %2" : "=v"(r) : "v"(a), "v"(b));
  return r;
}
__device__ inline f32x2 f8lo(uint32_t v){ return __builtin_amdgcn_cvt_pk_f32_fp8(v, false); }
__device__ inline f32x2 f8hi(uint32_t v){ return __builtin_amdgcn_cvt_pk_f32_fp8(v, true); }
__device__ inline u8 f2f8(float v){
  return (u8)(__builtin_amdgcn_cvt_pk_fp8_f32(v, v, 0, false) & 0xFF);
}

// ---------------- k_part: edge partition via LDS bucket buffers (r23-proven) -------------
__global__ __launch_bounds__(256) void k_part(const int* __restrict__ src,
                                              const int* __restrict__ dst, int e,
                                              int* __restrict__ gcur,
                                              uint32_t* __restrict__ gbuf, int n, int npb,
                                              const float* __restrict__ W1,
                                              const float* __restrict__ W2,
                                              ushort* __restrict__ W1t, ushort* __restrict__ W2t){
  __shared__ uint32_t pbuf[NB*PSLOTS];
  __shared__ int lcnt[NB];
  int b = blockIdx.x, t = threadIdx.x;
  int gidx = b*256 + t;
  if(gidx < FIN*FH){
    int k = gidx / FH, c = gidx % FH;
    W1t[(size_t)c*FIN + k] = f2bf(W1[gidx]);
  }
  if(gidx < 48*FH){
    int c = gidx / FH, k = gidx % FH;
    W2t[gidx] = (c < FOUT) ? f2bf(W2[(size_t)k*FOUT + c]) : (ushort)0;
  }
  for(int i=t;i<NB;i+=256) lcnt[i]=0;
  __syncthreads();
  int chunk = (e + PBLK - 1) / PBLK;
  int base = b * chunk;
  int endE = base + chunk; if(endE > e) endE = e;
  if(base >= e) return;
  int rounds = (endE - base + 255) / 256;
  for(int rr=0; rr<rounds; ++rr){
    int i = base + rr*256 + t;
    if(i < endE){
      int s = src[i];
      int d = dst[i];
      int bk = d / npb;
      uint32_t pk_ = ((uint32_t)s << 8) | (uint32_t)(d - bk*npb);
      int slot = atomicAdd(&lcnt[bk], 1);
      if(slot < PSLOTS){
        pbuf[bk*PSLOTS + slot] = pk_;
      } else {
        int g = atomicAdd(&gcur[bk], 1);
        gbuf[(size_t)bk*CAPG + g] = pk_;
      }
    }
    __syncthreads();
    bool last = (rr == rounds-1);
    for(int tb=t; tb<NB; tb+=256){
      int c = lcnt[tb];
      int k = c < PSLOTS ? c : PSLOTS;
      if(k > 0 && (k >= 16 || last)){
        int g = atomicAdd(&gcur[tb], k);
        uint32_t* dstp = &gbuf[(size_t)tb*CAPG + g];
        const uint32_t* srcp = &pbuf[tb*PSLOTS];
        for(int q=0; q<k; q++) dstp[q] = srcp[q];
        lcnt[tb] = 0;
      }
    }
    __syncthreads();
  }
}

// ---------------- k_scan_g: exclusive scan of gcur -> bucket CSR start offsets ----------
__global__ __launch_bounds__(512) void k_scan_g(const int* __restrict__ gcur,
                                                int* __restrict__ bstart){
  __shared__ int sh[512];
  int t = threadIdx.x;
  sh[t] = gcur[t];
  __syncthreads();
  for(int off=1; off<512; off<<=1){
    int x = (t>=off)? sh[t-off]:0; __syncthreads();
    sh[t]+=x; __syncthreads();
  }
  bstart[t] = (t>0)? sh[t-1] : 0;
}

// ---------------- k_histfill: per-bucket hist + local scan + rp/dinv + CSR scatter -------
__global__ __launch_bounds__(256) void k_histfill(const uint32_t* __restrict__ gbuf,
                                                  const int* __restrict__ gcur,
                                                  const int* __restrict__ bstart,
                                                  int* __restrict__ rp, float* __restrict__ dinv,
                                                  int* __restrict__ srcs, int n, int npb){
  __shared__ int hist[256];
  __shared__ int sh[256];
  __shared__ int lcur[256];
  int b = blockIdx.x, t = threadIdx.x;
  int base = b * npb;
  if(base >= n) return;
  int nn = n - base; if(nn > npb) nn = npb;
  hist[t] = 0;
  __syncthreads();
  int m = gcur[b];
  const uint32_t* bp = gbuf + (size_t)b*CAPG;
  for(int i=t; i<m; i+=256) atomicAdd(&hist[bp[i] & 255u], 1);
  __syncthreads();
  int v = hist[t];
  sh[t] = v;
  __syncthreads();
  for(int off=1; off<256; off<<=1){
    int x = (t>=off)? sh[t-off]:0; __syncthreads();
    sh[t]+=x; __syncthreads();
  }
  int bs = bstart[b];
  if(t < nn){
    rp[base+t+1] = bs + sh[t];            // global inclusive prefix
    dinv[base+t] = rsqrtf((float)(v+1));
    lcur[t] = bs + sh[t] - v;             // row start cursor
  }
  if(b==0 && t==0) rp[0] = 0;
  __syncthreads();
  for(int i=t; i<m; i+=256){
    uint32_t w = bp[i];
    int ld = (int)(w & 255u);
    int p = atomicAdd(&lcur[ld], 1);
    srcs[p] = (int)(w >> 8);
  }
}

// ---------------- gemm1: r16 structure, W1 staged in 4 x 32KB K-phases ----------------
// No VGPR cap (launch_bounds min-waves=2): LDS 32KB + ~68 VGPR -> ~3 blocks/CU (24 waves).
__global__ __launch_bounds__(512, 2) void k_gemm1(const float* __restrict__ X,
                                                  const ushort* __restrict__ W1t,
                                                  const float* __restrict__ dinv,
                                                  u8* __restrict__ XWs, int n){
  __shared__ char smem[32768];   // [128 cols][128 k] bf16, XOR-swizzled (per phase)
  int t = threadIdx.x;
  int gi = blockIdx.x;
  int lane = t & 63;
  int wid = t >> 6;
  int l15 = lane & 15;
  int lk8 = (lane >> 4) * 8;
  int rowbase = gi * 256 + wid * 32;

  int r0 = rowbase + l15;      if (r0 >= n) r0 = n-1;
  int r1 = rowbase + 16 + l15; if (r1 >= n) r1 = n-1;
  const float* a0p = X + (size_t)r0*FIN;
  const float* a1p = X + (size_t)r1*FIN;

  f32x4 acc[2][8];
  #pragma unroll
  for(int i=0;i<2;i++)
    #pragma unroll
    for(int j=0;j<8;j++) acc[i][j] = (f32x4){0.f,0.f,0.f,0.f};

  char* WsB = smem;

  for(int ph=0; ph<4; ph++){
    if(ph) __syncthreads();
    // stage 32KB: 2048 x 16B chunks, 512 thr -> 4 iters
    #pragma unroll
    for(int it=0; it<4; it++){
      int c = it*512 + t;
      int col = c >> 4, kslot = c & 15;
      uint4 v = *(const uint4*)(W1t + (size_t)col*FIN + ph*128 + kslot*8);
      int dstb = col*256 + ((kslot*16) ^ ((col & 7) << 4));
      *(uint4*)(WsB + dstb) = v;
    }
    __syncthreads();

    for(int kc=0; kc<4; kc++){
      int kl = kc*32 + lk8;             // local k within phase, 0..127
      int kg = ph*128 + kl;             // global k
      float4 a0a = *(const float4*)(a0p + kg);
      float4 a0b = *(const float4*)(a0p + kg + 4);
      float4 a1a = *(const float4*)(a1p + kg);
      float4 a1b = *(const float4*)(a1p + kg + 4);
      uint4 fa0u, fa1u;
      fa0u.x = cvtpk(a0a.x, a0a.y); fa0u.y = cvtpk(a0a.z, a0a.w);
      fa0u.z = cvtpk(a0b.x, a0b.y); fa0u.w = cvtpk(a0b.z, a0b.w);
      fa1u.x = cvtpk(a1a.x, a1a.y); fa1u.y = cvtpk(a1a.z, a1a.w);
      fa1u.z = cvtpk(a1b.x, a1b.y); fa1u.w = cvtpk(a1b.z, a1b.w);
      bf16x8 fa0 = *(bf16x8*)&fa0u;
      bf16x8 fa1 = *(bf16x8*)&fa1u;

      #pragma unroll
      for(int fj=0; fj<8; fj++){
        int col = fj*16 + l15;
        int srcb = col*256 + ((kl*2) ^ ((col & 7) << 4));
        bf16x8 fb = *(const bf16x8*)(WsB + srcb);
        acc[0][fj] = __builtin_amdgcn_mfma_f32_16x16x32_bf16(fa0, fb, acc[0][fj], 0, 0, 0);
        acc[1][fj] = __builtin_amdgcn_mfma_f32_16x16x32_bf16(fa1, fb, acc[1][fj], 0, 0, 0);
      }
    }
  }

  int rbase = (lane >> 4) * 4;
  #pragma unroll
  for(int fi=0; fi<2; fi++){
    #pragma unroll
    for(int r=0; r<4; r++){
      int row = rowbase + fi*16 + rbase + r;
      if(row < n){
        float dd = dinv[row];
        #pragma unroll
        for(int fj=0; fj<8; fj++){
          XWs[(size_t)row*FH + fj*16 + l15] = f2f8(acc[fi][fj][r] * dd);
        }
      }
    }
  }
}

// ---------------- agg1: H1b = relu(dd*(sum_s XWs[s] + XWs[d]) + b1), fp8 gather -----------
__global__ __launch_bounds__(256) void k_agg1(const u8* __restrict__ XWs, const int* __restrict__ rp,
                                              const int* __restrict__ srcs, const float* __restrict__ dinv,
                                              const float* __restrict__ b1, ushort* __restrict__ H1b, int n){
  int d = blockIdx.x*4 + (threadIdx.x >> 6);
  if(d >= n) return;
  int lane = threadIdx.x & 63;
  int g = lane >> 3, li = lane & 7;
  f32x2 acc[8];
  #pragma unroll
  for(int k=0;k<8;k++) acc[k] = (f32x2){0.f,0.f};
  int beg = rp[d];
  int end = rp[d+1];
  int j = beg + g;
  bool h0 = j < end, h1 = j + 8 < end;
  int s0 = 0, s1 = 0;
  if(h0) s0 = srcs[j];
  if(h1) s1 = srcs[j+8];
  while(h1){
    int nj = j + 16;
    bool nh0 = nj < end, nh1 = nj + 8 < end;
    int ns0 = 0, ns1 = 0;
    if(nh0) ns0 = srcs[nj];
    if(nh1) ns1 = srcs[nj+8];
    uint4 a0 = *(const uint4*)(XWs + (size_t)s0*FH + li*16);
    uint4 c0 = *(const uint4*)(XWs + (size_t)s1*FH + li*16);
    acc[0] = pkadd(acc[0], pkadd(f8lo(a0.x), f8lo(c0.x)));
    acc[1] = pkadd(acc[1], pkadd(f8hi(a0.x), f8hi(c0.x)));
    acc[2] = pkadd(acc[2], pkadd(f8lo(a0.y), f8lo(c0.y)));
    acc[3] = pkadd(acc[3], pkadd(f8hi(a0.y), f8hi(c0.y)));
    acc[4] = pkadd(acc[4], pkadd(f8lo(a0.z), f8lo(c0.z)));
    acc[5] = pkadd(acc[5], pkadd(f8hi(a0.z), f8hi(c0.z)));
    acc[6] = pkadd(acc[6], pkadd(f8lo(a0.w), f8lo(c0.w)));
    acc[7] = pkadd(acc[7], pkadd(f8hi(a0.w), f8hi(c0.w)));
    j = nj; s0 = ns0; s1 = ns1; h0 = nh0; h1 = nh1;
  }
  if(h0){
    uint4 a0 = *(const uint4*)(XWs + (size_t)s0*FH + li*16);
    acc[0] = pkadd(acc[0], f8lo(a0.x));
    acc[1] = pkadd(acc[1], f8hi(a0.x));
    acc[2] = pkadd(acc[2], f8lo(a0.y));
    acc[3] = pkadd(acc[3], f8hi(a0.y));
    acc[4] = pkadd(acc[4], f8lo(a0.z));
    acc[5] = pkadd(acc[5], f8hi(a0.z));
    acc[6] = pkadd(acc[6], f8lo(a0.w));
    acc[7] = pkadd(acc[7], f8hi(a0.w));
  }
  #pragma unroll
  for(int k=0;k<8;k++){
    #pragma unroll
    for(int c=0;c<2;c++){
      acc[k][c] += __shfl_xor(acc[k][c], 8);
      acc[k][c] += __shfl_xor(acc[k][c], 16);
      acc[k][c] += __shfl_xor(acc[k][c], 32);
    }
  }
  if(g == 0){
    uint4 sv4 = *(const uint4*)(XWs + (size_t)d*FH + li*16);
    f32x2 slf[8];
    slf[0]=f8lo(sv4.x); slf[1]=f8hi(sv4.x); slf[2]=f8lo(sv4.y); slf[3]=f8hi(sv4.y);
    slf[4]=f8lo(sv4.z); slf[5]=f8hi(sv4.z); slf[6]=f8lo(sv4.w); slf[7]=f8hi(sv4.w);
    float dd = dinv[d];
    uint32_t w[8];
    #pragma unroll
    for(int k=0;k<8;k++){
      float b0 = b1[li*16 + k*2];
      float b1v = b1[li*16 + k*2 + 1];
      float o0 = fmaxf((acc[k][0]+slf[k][0])*dd + b0, 0.f);
      float o1 = fmaxf((acc[k][1]+slf[k][1])*dd + b1v, 0.f);
      w[k] = cvtpk(o0, o1);
    }
    uint4 w0 = {w[0],w[1],w[2],w[3]};
    uint4 w1 = {w[4],w[5],w[6],w[7]};
    uint4* wp = (uint4*)(H1b + (size_t)d*FH + li*16);
    wp[0] = w0;
    wp[1] = w1;
  }
}

// ---------------- GEMM2 via MFMA: H2s[n,64] fp8 = (H1b @ W2) * dinv[row] ----------------
__global__ __launch_bounds__(256) void k_gemm2_mfma(const ushort* __restrict__ H1b,
                                                    const ushort* __restrict__ W2t,
                                                    const float* __restrict__ dinv,
                                                    u8* __restrict__ H2s, int n){
  int t = threadIdx.x;
  int lane = t & 63;
  int wid = t >> 6;
  int l15 = lane & 15;
  int lk8 = (lane >> 4) * 8;
  int rowbase = blockIdx.x * 128 + wid * 32;

  int r0 = rowbase + l15;      if (r0 >= n) r0 = n-1;
  int r1 = rowbase + 16 + l15; if (r1 >= n) r1 = n-1;
  const ushort* a0p = H1b + (size_t)r0*FH + lk8;
  const ushort* a1p = H1b + (size_t)r1*FH + lk8;

  f32x4 acc[2][3];
  #pragma unroll
  for(int i=0;i<2;i++)
    #pragma unroll
    for(int j=0;j<3;j++) acc[i][j] = (f32x4){0.f,0.f,0.f,0.f};

  #pragma unroll
  for(int kc=0; kc<4; kc++){
    int k0 = kc*32;
    bf16x8 fa0 = *(const bf16x8*)(a0p + k0);
    bf16x8 fa1 = *(const bf16x8*)(a1p + k0);
    #pragma unroll
    for(int fj=0; fj<3; fj++){
      bf16x8 fb = *(const bf16x8*)(W2t + (size_t)(fj*16 + l15)*FH + k0 + lk8);
      acc[0][fj] = __builtin_amdgcn_mfma_f32_16x16x32_bf16(fa0, fb, acc[0][fj], 0, 0, 0);
      acc[1][fj] = __builtin_amdgcn_mfma_f32_16x16x32_bf16(fa1, fb, acc[1][fj], 0, 0, 0);
    }
  }

  int rbase = (lane >> 4) * 4;
  #pragma unroll
  for(int fi=0; fi<2; fi++){
    #pragma unroll
    for(int r=0; r<4; r++){
      int row = rowbase + fi*16 + rbase + r;
      if(row < n){
        float dd = dinv[row];
        #pragma unroll
        for(int fj=0; fj<3; fj++){
          int col = fj*16 + l15;
          H2s[(size_t)row*FP + col] = (col < FOUT) ? f2f8(acc[fi][fj][r] * dd) : (u8)0;
        }
        H2s[(size_t)row*FP + 48 + l15] = (u8)0;
      }
    }
  }
}

// ---------------- agg2 + bias + log_softmax, fp8 gather ----------------
__global__ __launch_bounds__(256) void k_agg2_sm(const u8* __restrict__ H2s, const int* __restrict__ rp,
                                                 const int* __restrict__ srcs, const float* __restrict__ dinv,
                                                 const float* __restrict__ b2, float* __restrict__ out, int n){
  int d = blockIdx.x*4 + (threadIdx.x >> 6);
  if(d >= n) return;
  int lane = threadIdx.x & 63;
  int g = lane >> 3, li = lane & 7;
  f32x2 acc[4];
  #pragma unroll
  for(int k=0;k<4;k++) acc[k] = (f32x2){0.f,0.f};
  int beg = rp[d];
  int end = rp[d+1];
  int j = beg + g;
  bool h0 = j < end, h1 = j + 8 < end;
  int s0 = 0, s1 = 0;
  if(h0) s0 = srcs[j];
  if(h1) s1 = srcs[j+8];
  while(h1){
    int nj = j + 16;
    bool nh0 = nj < end, nh1 = nj + 8 < end;
    int ns0 = 0, ns1 = 0;
    if(nh0) ns0 = srcs[nj];
    if(nh1) ns1 = srcs[nj+8];
    uint2 v = *(const uint2*)(H2s + (size_t)s0*FP + li*8);
    uint2 u = *(const uint2*)(H2s + (size_t)s1*FP + li*8);
    acc[0] = pkadd(acc[0], pkadd(f8lo(v.x), f8lo(u.x)));
    acc[1] = pkadd(acc[1], pkadd(f8hi(v.x), f8hi(u.x)));
    acc[2] = pkadd(acc[2], pkadd(f8lo(v.y), f8lo(u.y)));
    acc[3] = pkadd(acc[3], pkadd(f8hi(v.y), f8hi(u.y)));
    j = nj; s0 = ns0; s1 = ns1; h0 = nh0; h1 = nh1;
  }
  if(h0){
    uint2 v = *(const uint2*)(H2s + (size_t)s0*FP + li*8);
    acc[0] = pkadd(acc[0], f8lo(v.x));
    acc[1] = pkadd(acc[1], f8hi(v.x));
    acc[2] = pkadd(acc[2], f8lo(v.y));
    acc[3] = pkadd(acc[3], f8hi(v.y));
  }
  #pragma unroll
  for(int k=0;k<4;k++){
    #pragma unroll
    for(int c=0;c<2;c++){
      acc[k][c] += __shfl_xor(acc[k][c], 8);
      acc[k][c] += __shfl_xor(acc[k][c], 16);
      acc[k][c] += __shfl_xor(acc[k][c], 32);
    }
  }
  uint2 sv = *(const uint2*)(H2s + (size_t)d*FP + li*8);
  f32x2 s2[4] = { f8lo(sv.x), f8hi(sv.x), f8lo(sv.y), f8hi(sv.y) };
  float dd = dinv[d];
  float val[8];
  #pragma unroll
  for(int k=0;k<4;k++){
    #pragma unroll
    for(int c=0;c<2;c++){
      int col = li*8 + k*2 + c;
      float bv = (col < FOUT) ? b2[col] : 0.f;
      val[k*2+c] = (col < FOUT) ? ((acc[k][c]+s2[k][c])*dd + bv) : -3.402823466e38f;
    }
  }
  float m = val[0];
  #pragma unroll
  for(int k=1;k<8;k++) m = fmaxf(m, val[k]);
  #pragma unroll
  for(int off=1; off<8; off<<=1) m = fmaxf(m, __shfl_xor(m, off));
  float ssum = 0.f;
  #pragma unroll
  for(int k=0;k<8;k++){
    int col = li*8 + k;
    ssum += (col < FOUT) ? expf(val[k] - m) : 0.f;
  }
  #pragma unroll
  for(int off=1; off<8; off<<=1) ssum += __shfl_xor(ssum, off);
  float lse = m + logf(ssum);
  if(g == 0 && li < 5){
    float4 o0 = {val[0]-lse, val[1]-lse, val[2]-lse, val[3]-lse};
    float4 o1 = {val[4]-lse, val[5]-lse, val[6]-lse, val[7]-lse};
    float* op = out + (size_t)d*FOUT + li*8;
    *(float4*)op = o0;
    *(float4*)(op+4) = o1;
  }
}

// ---------------- launch ----------------

extern "C" void kernel_launch(void* const* d_in, const int* in_sizes, int n_in,
                              void* d_out, int out_size, void* d_ws, size_t ws_size,
                              hipStream_t stream){
  const float* X  = (const float*)d_in[0];
  const int*   ei = (const int*)d_in[1];
  const float* W1 = (const float*)d_in[2];
  const float* b1 = (const float*)d_in[3];
  const float* W2 = (const float*)d_in[4];
  const float* b2 = (const float*)d_in[5];
  float* out = (float*)d_out;

  int n = in_sizes[0] / FIN;      // 100000
  int e = in_sizes[1] / 2;        // 1600000
  const int* src = ei;
  const int* dst = ei + e;

  int npb = (n + NB - 1) / NB;    // 196 (< 256, fits packed byte and lcur[256])

  // workspace layout
  u8* XWs     = (u8*)d_ws;                           // n*128 fp8 (dinv-scaled XW)
  ushort* H1b = (ushort*)(XWs + (size_t)n*FH);       // n*128 bf16 (gbuf overlay pre-agg1)
  u8* H2s     = (u8*)(H1b + (size_t)n*FH);           // n*64 fp8 (dinv-scaled, padded)
  ushort* W1t = (ushort*)(H2s + (size_t)n*FP);       // 128*512 bf16
  ushort* W2t = W1t + (size_t)FH*FIN;                // 48*128 bf16
  float* dinv = (float*)(W2t + 48*FH);               // n
  int* gcur   = (int*)(dinv + n);                    // NB
  int* bstart = gcur + NB;                           // NB
  int* rp     = bstart + NB;                         // n+1
  int* srcs   = rp + (n+1) + 3;                      // e
  uint32_t* gbuf = (uint32_t*)H1b;                   // NB*CAPG*4B = 8.4MB (< H1b's 25.6MB)

  int G = (n + 255) / 256;                   // gemm1 blocks (256 rows each)

  hipMemsetAsync(gcur, 0, (size_t)NB*sizeof(int), stream);
  hipLaunchKernelGGL(k_part, dim3(PBLK), dim3(256), 0, stream,
                     src, dst, e, gcur, gbuf, n, npb, W1, W2, W1t, W2t);
  hipLaunchKernelGGL(k_scan_g, dim3(1), dim3(512), 0, stream, gcur, bstart);
  hipLaunchKernelGGL(k_histfill, dim3(NB), dim3(256), 0, stream,
                     gbuf, gcur, bstart, rp, dinv, srcs, n, npb);

  hipLaunchKernelGGL(k_gemm1, dim3(G), dim3(512), 0, stream, X, W1t, dinv, XWs, n);

  hipLaunchKernelGGL(k_agg1, dim3((n+3)/4), dim3(256), 0, stream, XWs, rp, srcs, dinv, b1, H1b, n);
  hipLaunchKernelGGL(k_gemm2_mfma, dim3((n+127)/128), dim3(256), 0, stream, H1b, W2t, dinv, H2s, n);
  hipLaunchKernelGGL(k_agg2_sm, dim3((n+3)/4), dim3(256), 0, stream, H2s, rp, srcs, dinv, b2, out, n);
}